// Round 4
// baseline (274.056 us; speedup 1.0000x reference)
//
#include <hip/hip_runtime.h>
#include <math.h>

#define CH 85

// records per scale
static constexpr int RS = 16 * 76 * 76 * 3;   // 277248 (stride 8)
static constexpr int RM = 16 * 38 * 38 * 3;   //  69312 (stride 16)
static constexpr int RL = 16 * 19 * 19 * 3;   //  17328 (stride 32)
static constexpr int NREC = RS + RM + RL;     // 363888

// float4 element counts per scale (note exact 4 : 1 : 1/4 ratios)
static constexpr unsigned N4S = (unsigned)RS * 85u / 4u;  // 5,891,520
static constexpr unsigned N4M = (unsigned)RM * 85u / 4u;  // 1,472,880
static constexpr unsigned N4L = (unsigned)RL * 85u / 4u;  //   368,220

// stream family: per-scale block ranges, all with exactly 13 full iterations
static constexpr int SBLK = 1664;   // stride 425984: 13 full + rem 353728
static constexpr int MBLK = 416;    // stride 106496: 13 full + rem  88432
static constexpr int LBLK = 104;    // stride  26624: 13 full + rem  22108
static constexpr int NBLKA = SBLK + MBLK + LBLK;     // 2184

static constexpr unsigned REM_S = N4S - 13u * (unsigned)(SBLK * 256);
static constexpr unsigned REM_M = N4M - 13u * (unsigned)(MBLK * 256);
static constexpr unsigned REM_L = N4L - 13u * (unsigned)(LBLK * 256);

// record family: 1 thread per record
static constexpr int NBLKB    = (NREC + 255) / 256;  // 1422
static constexpr int NBLK_TOT = NBLKA + NBLKB;       // 3606

// partial-buffer layout in workspace
static constexpr int PB_CIOU = NBLKA;               // NBLKB entries
static constexpr int PB_CONF = NBLKA + NBLKB;       // NBLKB entries
static constexpr int PB_PRB2 = NBLKA + 2 * NBLKB;   // NBLKB entries (corr, negative)

__constant__ float c_anchors[18] = {
    12.f, 16.f, 19.f, 36.f, 40.f, 28.f,        // s (stride 8)
    36.f, 75.f, 76.f, 55.f, 72.f, 146.f,       // m (stride 16)
    142.f, 110.f, 192.f, 243.f, 459.f, 401.f   // l (stride 32)
};

__device__ __forceinline__ float fast_rcp(float x) {
    return __builtin_amdgcn_rcpf(x);
}
__device__ __forceinline__ float sigm(float x) {
    return fast_rcp(1.f + __expf(-x));
}
__device__ __forceinline__ float softplusf(float x) {
    // log(1 + e^x), stable
    return fmaxf(x, 0.f) + __logf(1.f + __expf(-fabsf(x)));
}

// BCE over one float4-pair; record-crossing handled branchlessly
__device__ __forceinline__ void bce4(const float* __restrict__ cb,
                                     const float* __restrict__ lb,
                                     unsigned i4, unsigned rmax, float& acc)
{
    unsigned el = i4 * 4u;
    float4 cv = *reinterpret_cast<const float4*>(cb + el);
    float4 lv = *reinterpret_cast<const float4*>(lb + el);
    unsigned rA  = el / 85u;                      // magic-mul
    unsigned rem = (rA + 1u) * 85u - el;          // 1..85 floats left in record
    unsigned rB  = rA + 1u; if (rB > rmax) rB = rmax;   // OOB guard
    float respA = lb[rA * 85u + 4u];              // near-uniform gather, stream-hot
    float respB = lb[rB * 85u + 4u];
    float r1 = (rem <= 1u) ? respB : respA;
    float r2 = (rem <= 2u) ? respB : respA;
    float r3 = (rem <= 3u) ? respB : respA;
    acc = fmaf(respA, fmaf(-lv.x, cv.x, softplusf(cv.x)), acc);
    acc = fmaf(r1,    fmaf(-lv.y, cv.y, softplusf(cv.y)), acc);
    acc = fmaf(r2,    fmaf(-lv.z, cv.z, softplusf(cv.z)), acc);
    acc = fmaf(r3,    fmaf(-lv.w, cv.w, softplusf(cv.w)), acc);
}

__global__ __launch_bounds__(256) void yolo_main(
    const float* __restrict__ conv_l, const float* __restrict__ conv_m,
    const float* __restrict__ conv_s, const float* __restrict__ lab_s,
    const float* __restrict__ lab_m, const float* __restrict__ lab_l,
    const float* __restrict__ tb, float* __restrict__ pb)
{
    int blk = blockIdx.x;
    int t   = threadIdx.x;

    float ciou_acc = 0.f, conf_acc = 0.f, prob_acc = 0.f;

    if (blk < NBLKA) {
        // ======= stream family: scale resolved ONCE per block, uniform loop =======
        const float* cb; const float* lb;
        unsigned tid, stride, remN, rmax;
        if (blk < SBLK) {
            cb = conv_s; lb = lab_s;
            tid = (unsigned)(blk * 256 + t);            stride = SBLK * 256;
            remN = REM_S;                               rmax = (unsigned)RS - 1u;
        } else if (blk < SBLK + MBLK) {
            cb = conv_m; lb = lab_m;
            tid = (unsigned)((blk - SBLK) * 256 + t);   stride = MBLK * 256;
            remN = REM_M;                               rmax = (unsigned)RM - 1u;
        } else {
            cb = conv_l; lb = lab_l;
            tid = (unsigned)((blk - SBLK - MBLK) * 256 + t); stride = LBLK * 256;
            remN = REM_L;                               rmax = (unsigned)RL - 1u;
        }

        #pragma unroll
        for (int k = 0; k < 13; ++k)
            bce4(cb, lb, tid + (unsigned)k * stride, rmax, prob_acc);
        if (tid < remN)
            bce4(cb, lb, tid + 13u * stride, rmax, prob_acc);
    } else {
        // ================= record family: 1 thread per record =================
        int g = (blk - NBLKA) * 256 + t;
        if (g < NREC) {
            const float* conv; const float* lab;
            int S; float stride; int ao; unsigned gl;
            if (g < RS) {
                conv = conv_s; lab = lab_s; S = 76; stride = 8.f;  ao = 0;  gl = (unsigned)g;
            } else if (g < RS + RM) {
                conv = conv_m; lab = lab_m; S = 38; stride = 16.f; ao = 6;  gl = (unsigned)(g - RS);
            } else {
                conv = conv_l; lab = lab_l; S = 19; stride = 32.f; ao = 12; gl = (unsigned)(g - RS - RM);
            }
            const float* cr = conv + (size_t)gl * CH;
            const float* lr = lab  + (size_t)gl * CH;
            float c0 = cr[0], c1 = cr[1], c2v = cr[2], c3 = cr[3], c4 = cr[4];
            float l0 = lr[0], l1 = lr[1], l2  = lr[2], l3 = lr[3], resp = lr[4];

            // subtract the spurious BCE the stream family added for channels 0..4
            float corr = fmaf(-l0,   c0,  softplusf(c0))
                       + fmaf(-l1,   c1,  softplusf(c1))
                       + fmaf(-l2,   c2v, softplusf(c2v))
                       + fmaf(-l3,   c3,  softplusf(c3))
                       + fmaf(-resp, c4,  softplusf(c4));
            prob_acc = -resp * corr;

            unsigned a = gl % 3u; unsigned q = gl / 3u;
            unsigned j = q % (unsigned)S; q /= (unsigned)S;
            unsigned i = q % (unsigned)S; unsigned b = q / (unsigned)S;

            float lx = l0, ly = l1, lw = l2, lh = l3;

            // decode
            float px = (sigm(c0) + (float)j) * stride;
            float py = (sigm(c1) + (float)i) * stride;
            float pw = __expf(c2v) * c_anchors[ao + 2 * a];
            float ph = __expf(c3)  * c_anchors[ao + 2 * a + 1];

            // CIoU vs label
            float hx = 0.5f * pw, hy = 0.5f * ph;
            float b1x1 = px - hx, b1y1 = py - hy, b1x2 = px + hx, b1y2 = py + hy;
            float hlx = 0.5f * lw, hly = 0.5f * lh;
            float b2x1 = lx - hlx, b2y1 = ly - hly, b2x2 = lx + hlx, b2y2 = ly + hly;

            float area1 = (b1x2 - b1x1) * (b1y2 - b1y1);
            float area2 = (b2x2 - b2x1) * (b2y2 - b2y1);
            float lux = fmaxf(b1x1, b2x1), luy = fmaxf(b1y1, b2y1);
            float rdx = fminf(b1x2, b2x2), rdy = fminf(b1y2, b2y2);
            float iw = fmaxf(rdx - lux, 0.f), ih = fmaxf(rdy - luy, 0.f);
            float inter = iw * ih;
            float uni = area1 + area2 - inter;
            float iou = inter / (uni + 1e-9f);

            float encw = fmaxf(b1x2, b2x2) - fminf(b1x1, b2x1);
            float ench = fmaxf(b1y2, b2y2) - fminf(b1y1, b2y1);
            float cc2 = encw * encw + ench * ench;
            float dx = px - lx, dy = py - ly;
            float p2 = dx * dx + dy * dy;
            float at1 = atanf(pw / (ph + 1e-9f));
            float at2 = atanf(lw / (lh + 1e-9f));
            float dat = at1 - at2;
            const float FOUR_OVER_PI2 = 0.40528473456935109f;  // 4/pi^2
            float v = FOUR_OVER_PI2 * dat * dat;
            float al = v / (1.f - iou + v);
            float ciou = iou - p2 / cc2 - al * v;
            float bscale = 2.f - lw * lh * (1.f / (608.f * 608.f));
            ciou_acc = resp * bscale * (1.f - ciou);

            // conf loss: max IoU vs 70 true boxes of batch b
            const float4* tb4 = reinterpret_cast<const float4*>(tb) + (size_t)b * 70;
            float parea = pw * ph;
            float maxiou = 0.f;
            #pragma unroll 5
            for (int n = 0; n < 70; n++) {
                float4 tbx = tb4[n];
                float tx = tbx.x, ty = tbx.y, tw = tbx.z, th = tbx.w;
                float tx1 = tx - 0.5f * tw, ty1 = ty - 0.5f * th;
                float tx2 = tx + 0.5f * tw, ty2 = ty + 0.5f * th;
                float ix1 = fmaxf(b1x1, tx1), iy1 = fmaxf(b1y1, ty1);
                float ix2 = fminf(b1x2, tx2), iy2 = fminf(b1y2, ty2);
                float iiw = fmaxf(ix2 - ix1, 0.f), iih = fmaxf(iy2 - iy1, 0.f);
                float ia = iiw * iih;
                float u = parea + tw * th - ia;
                maxiou = fmaxf(maxiou, ia * fast_rcp(u));
            }
            float rbgd = (1.f - resp) * (maxiou < 0.5f ? 1.f : 0.f);
            float spc = softplusf(c4);
            conf_acc = resp * (spc - c4) + rbgd * spc;
        }
    }

    // ---- block reduce → per-block partials ----
    for (int off = 32; off > 0; off >>= 1) {
        ciou_acc += __shfl_down(ciou_acc, off);
        conf_acc += __shfl_down(conf_acc, off);
        prob_acc += __shfl_down(prob_acc, off);
    }
    __shared__ float red[4][3];
    int lane = threadIdx.x & 63, wv = threadIdx.x >> 6;
    if (lane == 0) { red[wv][0] = ciou_acc; red[wv][1] = conf_acc; red[wv][2] = prob_acc; }
    __syncthreads();
    if (threadIdx.x == 0) {
        float pr = red[0][2] + red[1][2] + red[2][2] + red[3][2];
        if (blk < NBLKA) {
            pb[blk] = pr;
        } else {
            int gb = blk - NBLKA;
            pb[PB_CIOU + gb] = red[0][0] + red[1][0] + red[2][0] + red[3][0];
            pb[PB_CONF + gb] = red[0][1] + red[1][1] + red[2][1] + red[3][1];
            pb[PB_PRB2 + gb] = pr;
        }
    }
}

__global__ __launch_bounds__(256) void finalize_k(const float* __restrict__ pb,
                                                  float* __restrict__ out)
{
    double s0 = 0.0, s1 = 0.0, s2 = 0.0;
    for (int i = threadIdx.x; i < NBLKA; i += 256)
        s2 += (double)pb[i];                       // stream prob
    for (int i = threadIdx.x; i < NBLKB; i += 256) {
        s0 += (double)pb[PB_CIOU + i];
        s1 += (double)pb[PB_CONF + i];
        s2 += (double)pb[PB_PRB2 + i];             // prob correction (negative)
    }
    for (int off = 32; off > 0; off >>= 1) {
        s0 += __shfl_down(s0, off);
        s1 += __shfl_down(s1, off);
        s2 += __shfl_down(s2, off);
    }
    __shared__ double rd[4][3];
    int lane = threadIdx.x & 63, wv = threadIdx.x >> 6;
    if (lane == 0) { rd[wv][0] = s0; rd[wv][1] = s1; rd[wv][2] = s2; }
    __syncthreads();
    if (threadIdx.x == 0) {
        float ci = (float)((rd[0][0] + rd[1][0] + rd[2][0] + rd[3][0]) / 16.0);
        float co = (float)((rd[0][1] + rd[1][1] + rd[2][1] + rd[3][1]) / 16.0);
        float pr = (float)((rd[0][2] + rd[1][2] + rd[2][2] + rd[3][2]) / 16.0);
        out[0] = ci + co + pr;
        out[1] = ci;
        out[2] = co;
        out[3] = pr;
    }
}

extern "C" void kernel_launch(void* const* d_in, const int* in_sizes, int n_in,
                              void* d_out, int out_size, void* d_ws, size_t ws_size,
                              hipStream_t stream) {
    const float* conv_l = (const float*)d_in[0];
    const float* conv_m = (const float*)d_in[1];
    const float* conv_s = (const float*)d_in[2];
    const float* lab_s  = (const float*)d_in[3];
    const float* lab_m  = (const float*)d_in[4];
    const float* lab_l  = (const float*)d_in[5];
    const float* tb     = (const float*)d_in[6];
    float* pb  = (float*)d_ws;   // NBLKA + 3*NBLKB floats of partials
    float* out = (float*)d_out;

    yolo_main<<<NBLK_TOT, 256, 0, stream>>>(conv_l, conv_m, conv_s,
                                            lab_s, lab_m, lab_l, tb, pb);
    finalize_k<<<1, 256, 0, stream>>>(pb, out);
}